// Round 9
// baseline (257.967 us; speedup 1.0000x reference)
//
#include <hip/hip_runtime.h>
#include <hip/hip_bf16.h>

// CausalAttention: B=4, S=2048, d=1024, single head, causal. fp32 I/O, bf16 MFMA inside.
//
// R9: load-balancing round (R8 showed GEMM is per-block-latency bound; traffic fix
//     was neutral -> stop tuning K-loop, fix work distribution):
//     (1) scores: 256x128 -> 128x128 tiles (544 quanta vs 288: kills the 1.125/CU tail)
//     (2) PV: new paired mode -- one 8-wave block does stripes y and 15-y, total
//         K-iters 34 == constant; 256 uniform blocks, no Kend imbalance.
//     (3) template generalized (NT=2 wave-tiles) for the 8-wave 128-tile config.
//
// Pipeline:
//   1) Wq/Wk/Wv fp32 -> bf16 transposed, stacked Wt [3072][1024]
//   2) x fp32 -> bf16 Xb
//   3) {Q,K,V} = Xb * Wt^T                         (mode 3, 256x128, 8 waves)
//   4) zero rowsum; Vt = V^T per batch
//   5) E = masked-exp(Q*K^T/32) + rowsum atomics   (mode 1, 128x128, 4 waves)
//   6) out(fp32) = (E*V)/rowsum, paired stripes    (mode 4, 128x128, 8 waves)

typedef __bf16 bf16_t;
typedef __bf16 bf16x8 __attribute__((ext_vector_type(8)));
typedef float f32x4 __attribute__((ext_vector_type(4)));

__device__ __forceinline__ void load_lds16(const bf16_t* g, bf16_t* l) {
  __builtin_amdgcn_global_load_lds(
      (__attribute__((address_space(1))) void*)(void*)g,
      (__attribute__((address_space(3))) void*)l,
      16, 0, 0);
}

// C[m][n] = sum_k A[m][k]*B[n][k]  (A:[M][K], B:[N][K] row-major bf16)
// mode 1: scores (skip tiles above diag; epilogue mask+exp+rowsum-atomic)
// mode 3: fused qkv (colBase/1024 selects C0/C1/C2)
// mode 4: paired pv (block y does stripes y and NS-1-y; K clamped; scale by 1/rowsum)
// LDS swizzle: chunk position p of row r holds global chunk p^(r&7) -> 0 conflicts (R5-R8).
template <int BMv, int BNv, int NW, typename OT>
__global__ __launch_bounds__(NW * 64)
void gemm_nt_bf16(const bf16_t* __restrict__ A, const bf16_t* __restrict__ B,
                  OT* __restrict__ C0, OT* __restrict__ C1, OT* __restrict__ C2,
                  float* __restrict__ RS,
                  int M, int K, int ldc,
                  long strideA, long strideB, long strideC, int mode)
{
  constexpr int MW  = BMv / 64;        // waves along m
  constexpr int NWn = NW / MW;         // waves along n
  constexpr int WN  = BNv / NWn;       // wave n-extent (64 or 32)
  constexpr int NT  = WN / 16;         // n-subtiles per wave (4 or 2)
  constexpr int RA  = BMv / NW;        // rows staged per wave (A)
  constexpr int RB  = BNv / NW;        // rows staged per wave (B)

  // XCD-aware remap: pin all x-blocks of an A-panel (y,z) to one XCD (kept from R8:
  // FETCH -45%; requires (gy*gz)%8==0, true for all launches here).
  const int gx = gridDim.x, gy = gridDim.y;
  const int NP = gy * gridDim.z;
  const int P  = NP >> 3;
  const int flat = blockIdx.x + gx * (blockIdx.y + gy * blockIdx.z);
  const int i    = flat >> 3;
  const int pan  = (flat & 7) * P + (i % P);
  const int bx   = i / P;
  int by = pan % gy;
  const int bz   = pan / gy;
  if (mode == 1) by = gy - 1 - by;     // heavy-first for triangular grid

  const int colBase = bx * BNv;
  if (mode == 1 && colBase >= by * BMv + BMv) return;  // fully-masked score tile

  __shared__ __align__(16) bf16_t sA[BMv * 64];
  __shared__ __align__(16) bf16_t sB[BNv * 64];

  A += (size_t)bz * strideA;
  B += (size_t)bz * strideB;
  float* rs_b = RS + (size_t)bz * 2048;

  const int tid  = threadIdx.x;
  const int wave = tid >> 6;
  const int lane = tid & 63;
  const int quad = lane >> 4;
  const int ln16 = lane & 15;

  const int wm = (wave % MW) * 64;
  const int wn = (wave / MW) * WN;

  const int rA = lane >> 3;                       // 0..7 row-in-group
  const int sColOff = ((lane & 7) ^ rA) * 8;      // swizzled 16B-chunk offset
  const bf16_t* pB = B + (size_t)(colBase + wave * RB + rA) * K + sColOff;
  bf16_t* ldsA = sA + wave * RA * 64;
  bf16_t* ldsB = sB + wave * RB * 64;

  const int nHalf = (mode == 4) ? 2 : 1;
  const int NS = (mode == 4) ? 2 * gy : 0;        // total stripes for paired pv

  for (int h = 0; h < nHalf; h++) {
    const int stripe = (mode == 4) ? (h == 0 ? by : NS - 1 - by) : by;
    const int rowBase = stripe * BMv;
    const bf16_t* pA = A + (size_t)(rowBase + wave * RA + rA) * K + sColOff;

    f32x4 acc[4][NT] = {};

    const int Kend = (mode == 4) ? (K < rowBase + BMv ? K : rowBase + BMv) : K;

    for (int k0 = 0; k0 < Kend; k0 += 64) {
#pragma unroll
      for (int j = 0; j < RA / 8; j++)
        load_lds16(pA + k0 + (size_t)(8 * j) * K, ldsA + j * 512);
#pragma unroll
      for (int j = 0; j < RB / 8; j++)
        load_lds16(pB + k0 + (size_t)(8 * j) * K, ldsB + j * 512);
      __syncthreads();   // drains vmcnt for all waves

#pragma unroll
      for (int kk = 0; kk < 2; kk++) {
        bf16x8 af[4], bfr[NT];
#pragma unroll
        for (int mt = 0; mt < 4; mt++) {
          const int row = wm + mt * 16 + ln16;
          af[mt] = *(const bf16x8*)(sA + row * 64 + (((kk * 4 + quad) ^ (row & 7)) * 8));
        }
#pragma unroll
        for (int nt = 0; nt < NT; nt++) {
          const int row = wn + nt * 16 + ln16;
          bfr[nt] = *(const bf16x8*)(sB + row * 64 + (((kk * 4 + quad) ^ (row & 7)) * 8));
        }
#pragma unroll
        for (int mt = 0; mt < 4; mt++)
#pragma unroll
          for (int nt = 0; nt < NT; nt++)
            acc[mt][nt] = __builtin_amdgcn_mfma_f32_16x16x32_bf16(af[mt], bfr[nt], acc[mt][nt], 0, 0, 0);
      }
      __syncthreads();
    }

    // output target: mode 3 splits by 1024-col groups (uniform per block)
    OT* Cw = C0;
    int cb = colBase;
    if (mode == 3) {
      const int which = colBase >> 10;
      Cw = (which == 0) ? C0 : (which == 1) ? C1 : C2;
      cb = colBase & 1023;
    }
    Cw += (size_t)bz * strideC;

    // epilogue: C/D layout col = lane&15, row = quad*4 + r  [measured m89/m91]
#pragma unroll
    for (int mt = 0; mt < 4; mt++) {
#pragma unroll
      for (int r = 0; r < 4; r++) {
        const int row = rowBase + wm + mt * 16 + quad * 4 + r;
        float rsum = 0.0f;
        float rinv = 1.0f;
        if (mode == 4) rinv = 1.0f / rs_b[row];
#pragma unroll
        for (int nt = 0; nt < NT; nt++) {
          const int col = cb + wn + nt * 16 + ln16;
          float v = acc[mt][nt][r];
          if (mode == 1) {
            const float e = (col <= row) ? __expf(v * 0.03125f) : 0.0f;  // s/sqrt(1024)
            rsum += e;
            v = e;
          } else if (mode == 4) {
            v *= rinv;
          }
          Cw[(size_t)row * ldc + col] = (OT)v;
        }
        if (mode == 1) {
          rsum += __shfl_xor(rsum, 1, 64);
          rsum += __shfl_xor(rsum, 2, 64);
          rsum += __shfl_xor(rsum, 4, 64);
          rsum += __shfl_xor(rsum, 8, 64);
          if (ln16 == 0) atomicAdd(rs_b + row, rsum);
        }
      }
    }
    if (h + 1 < nHalf) __syncthreads();  // LDS reuse safety between halves
  }
}

// three fp32 [D][D] -> bf16 transposed, stacked [3D][D]; z selects source
__global__ __launch_bounds__(256)
void transpose_cvt3(const float* __restrict__ w0, const float* __restrict__ w1,
                    const float* __restrict__ w2, bf16_t* __restrict__ out, int D)
{
  const float* in = (blockIdx.z == 0) ? w0 : (blockIdx.z == 1) ? w1 : w2;
  bf16_t* o = out + (size_t)blockIdx.z * D * D;
  __shared__ float tile[32][33];
  const int c0 = blockIdx.x * 32, r0 = blockIdx.y * 32;
  const int tx = threadIdx.x, ty = threadIdx.y;  // (32, 8)
#pragma unroll
  for (int i = 0; i < 32; i += 8)
    tile[ty + i][tx] = in[(size_t)(r0 + ty + i) * D + (c0 + tx)];
  __syncthreads();
#pragma unroll
  for (int i = 0; i < 32; i += 8)
    o[(size_t)(c0 + ty + i) * D + (r0 + tx)] = (bf16_t)tile[tx][ty + i];
}

// bf16 [R][C] -> bf16 transposed [C][R]; batched via blockIdx.z
__global__ __launch_bounds__(256)
void transpose16(const unsigned short* __restrict__ in, unsigned short* __restrict__ out,
                 int R, int C)
{
  __shared__ unsigned short tile[32][33];
  const size_t bo = (size_t)blockIdx.z * R * C;
  const int c0 = blockIdx.x * 32, r0 = blockIdx.y * 32;
  const int tx = threadIdx.x, ty = threadIdx.y;  // (32, 8)
#pragma unroll
  for (int i = 0; i < 32; i += 8)
    tile[ty + i][tx] = in[bo + (size_t)(r0 + ty + i) * C + (c0 + tx)];
  __syncthreads();
#pragma unroll
  for (int i = 0; i < 32; i += 8)
    out[bo + (size_t)(c0 + ty + i) * R + (r0 + tx)] = tile[tx][ty + i];
}

// fp32 -> bf16 elementwise, 8/thread, vector load+store
__global__ __launch_bounds__(256)
void cvt_f32_bf16(const float* __restrict__ in, bf16_t* __restrict__ out, long n)
{
  long i = ((long)blockIdx.x * 256 + threadIdx.x) * 8;
  if (i + 7 < n) {
    float4 a = *(const float4*)(in + i);
    float4 b = *(const float4*)(in + i + 4);
    bf16x8 o;
    o[0] = (bf16_t)a.x; o[1] = (bf16_t)a.y; o[2] = (bf16_t)a.z; o[3] = (bf16_t)a.w;
    o[4] = (bf16_t)b.x; o[5] = (bf16_t)b.y; o[6] = (bf16_t)b.z; o[7] = (bf16_t)b.w;
    *(bf16x8*)(out + i) = o;
  }
}

__global__ __launch_bounds__(256)
void zero_f32(float* __restrict__ p, int n)
{
  const int i = blockIdx.x * 256 + threadIdx.x;
  if (i < n) p[i] = 0.0f;
}

extern "C" void kernel_launch(void* const* d_in, const int* in_sizes, int n_in,
                              void* d_out, int out_size, void* d_ws, size_t ws_size,
                              hipStream_t stream) {
  const float* x  = (const float*)d_in[0];
  const float* Wq = (const float*)d_in[1];
  const float* Wk = (const float*)d_in[2];
  const float* Wv = (const float*)d_in[3];
  float* out = (float*)d_out;

  const int Bb = 4, S = 2048, D = 1024;
  const int M = Bb * S;  // 8192

  // ws (bf16 elems): Q | K | Vt | Wt(3*D*D) | Xb | V   = 90,177,536 B (proven fit)
  // Sc (Bb*S*S == 2*M*D) aliases [Xb|V]; rowsum (32 KB f32) reuses Wt (dead post-QKV).
  bf16_t* ws = (bf16_t*)d_ws;
  bf16_t* Q   = ws;
  bf16_t* Kp  = Q  + (size_t)M * D;
  bf16_t* Vt  = Kp + (size_t)M * D;
  bf16_t* Wt  = Vt + (size_t)M * D;          // [3072][1024] stacked
  bf16_t* Xb  = Wt + 3 * (size_t)D * D;
  bf16_t* V   = Xb + (size_t)M * D;
  bf16_t* Sc  = Xb;
  float*  rowsum = (float*)Wt;               // Bb*S floats

  const dim3 tb(32, 8);

  // 1) W fp32 -> bf16 transposed, stacked
  transpose_cvt3<<<dim3(D / 32, D / 32, 3), tb, 0, stream>>>(Wq, Wk, Wv, Wt, D);

  // 2) x -> bf16
  cvt_f32_bf16<<<dim3((M * D) / (256 * 8)), dim3(256), 0, stream>>>(x, Xb, (long)M * D);

  // 3) fused projections: {Q,K,V} = Xb * Wt^T  (grid 24 x 32; 32 panels -> 4/XCD)
  gemm_nt_bf16<256, 128, 8, bf16_t><<<dim3(3 * D / 128, M / 256, 1), dim3(512), 0, stream>>>(
      Xb, Wt, Q, Kp, V, rowsum, M, D, D, 0, 0, 0, 3);

  // 4) zero rowsum (Wt dead now); Vt per batch
  zero_f32<<<dim3(M / 256), dim3(256), 0, stream>>>(rowsum, M);
  transpose16<<<dim3(D / 32, S / 32, Bb), tb, 0, stream>>>((const unsigned short*)V, (unsigned short*)Vt, S, D);

  // 5) E = masked-exp(Q*K^T/32) + rowsum  (128-tiles: 544 active quanta, 4-wave)
  gemm_nt_bf16<128, 128, 4, bf16_t><<<dim3(S / 128, S / 128, Bb), dim3(256), 0, stream>>>(
      Q, Kp, Sc, Sc, Sc, rowsum, S, D, S, (long)S * D, (long)S * D, (long)S * S, 1);

  // 6) out(fp32) = (E*V)/rowsum  paired stripes: 256 uniform blocks, 8-wave
  gemm_nt_bf16<128, 128, 8, float><<<dim3(D / 128, S / 256, Bb), dim3(512), 0, stream>>>(
      Sc, Vt, out, out, out, rowsum, S, S, D, (long)S * S, (long)D * S, (long)S * D, 4);
}